// Round 9
// baseline (681.500 us; speedup 1.0000x reference)
//
#include <hip/hip_runtime.h>
#include <stdint.h>

// HamiltonianFlow: x [256, 8, 32, 2] (q,p); H = 0.5*sum(p^2) + MLP(q).
// dq/dt = p, dp/dt = -W1 @ [(1-tanh(z)^2) * W2], z = q^T W1 + b1.
// 100 RK4 steps = 400 strictly sequential fwd+bwd 256x256 matvecs.
//
// R9: switch MFMA shape 16x16x32 -> 32x32x16. Per-block MFMA count is
// invariant to trajectory packing (R8 lesson: packing just idles CUs), but
// the 32x32 shape halves instruction count: 8 tile-rows x 16 K-chunks x 2
// dirs = 256 MFMA/block-eval -> 64/SIMD x 8.07 cyc = 516 cyc/eval floor
// (86 us whole problem) vs 1242 for 16x16. All 256 CUs active again
// (256 blocks, 1 traj each). R8's 2.8e7 bank conflicts came from the
// traj-split B-reads; single-traj B-frags read only 2 distinct rows/wave
// (banks 0-3/4-7) -> conflict-free broadcast.
//
// mfma_f32_32x32x16_f16 layouts: A[m=lane&31][k=8*(lane>>5)+j];
// B[k=8*(lane>>5)+j][n=lane&31]; D col=lane&31,
// row=(reg&3)+8*(reg>>2)+4*(lane>>5)  [m74/m101-verified C/D].
// fwd : A = W^T tile-row frags, B = q replicated -> D rows = z
// bwd : A = W   tile-row frags, B = u replicated -> D rows = g
// Lane l owns comp = 32w + (l&3) + 8*((l>>2)&3) + 4*(l>>5)  (lanes l, l^16
// duplicate); z/g extracted via 15-cndmask tree -> NO LDS bounce either dir.
// 8 waves (2/SIMD) co-issue to hide MFMA chain latency. 2 barriers/eval.
// FULL unroll on all reg arrays (R4: dynamic index => scratch spill).
// Numerics: f16 storage, fp32 MFMA accumulate (R3/5/7/8 class, 1.95e-3).

typedef _Float16 v8h __attribute__((ext_vector_type(8)));
typedef _Float16 v4h __attribute__((ext_vector_type(4)));
typedef float v4f __attribute__((ext_vector_type(4)));
typedef float v16f __attribute__((ext_vector_type(16)));

#define NSTEPS 100
#define WS 264   // padded f16 row stride (528 B: rows 16B-aligned)

__device__ __forceinline__ float pick16(v16f C, int r0, int r2) {
    // value at reg index r0 + 4*r2, all indices compile-time in the tree
    v4f g = (r2 == 0) ? (v4f){C[0], C[1], C[2], C[3]}
          : (r2 == 1) ? (v4f){C[4], C[5], C[6], C[7]}
          : (r2 == 2) ? (v4f){C[8], C[9], C[10], C[11]}
                      : (v4f){C[12], C[13], C[14], C[15]};
    return (r0 == 0) ? g.x : (r0 == 1) ? g.y : (r0 == 2) ? g.z : g.w;
}

__global__ __launch_bounds__(512, 2)
void ham_kernel(const float* __restrict__ x0, const float* __restrict__ W1,
                const float* __restrict__ b1, const float* __restrict__ W2,
                float* __restrict__ out)
{
    __shared__ __align__(16) _Float16 wlds[256 * WS];   // 135168 B staged W1
    __shared__ __align__(16) _Float16 qsh[256];
    __shared__ __align__(16) _Float16 ush[256];

    const int t = threadIdx.x;
    const int w = t >> 6;            // wave 0..7: owns comps [32w, 32w+32)
    const int l = t & 63;
    const int col = l & 31;
    const int half = l >> 5;         // K-subgroup of A/B frags
    const int r0 = l & 3;            // reg & 3
    const int r2 = (l >> 2) & 3;     // reg >> 2
    const int comp = 32 * w + r0 + 8 * r2 + 4 * half;   // owned component
    const bool iow = ((l & 16) == 0);                   // dedup lane pair
    const int blk = blockIdx.x;

    // ---- stage W1 -> LDS f16 (padded rows), coalesced ----
    #pragma unroll 1
    for (int k = t; k < 65536 / 4; k += 512) {
        const int row = k >> 6, col4 = (k & 63) * 4;
        float4 v = ((const float4*)W1)[k];
        v4h h; h[0] = (_Float16)v.x; h[1] = (_Float16)v.y;
               h[2] = (_Float16)v.z; h[3] = (_Float16)v.w;
        *(v4h*)(wlds + row * WS + col4) = h;
    }
    __syncthreads();

    // ---- weight frags, both orientations, FULL unroll ----
    // wA[kk] (fwd, A = W^T tile-row w): elem j = W[16kk+8half+j][32w+col]
    // wB[kk] (bwd, A = W   tile-row w): elem j = W[32w+col][16kk+8half+j]
    v8h wA[16], wB[16];
    #pragma unroll
    for (int kk = 0; kk < 16; ++kk) {
        wB[kk] = *(const v8h*)(wlds + (32 * w + col) * WS + 16 * kk + 8 * half);
        #pragma unroll
        for (int j = 0; j < 8; ++j)
            wA[kk][j] = wlds[(16 * kk + 8 * half + j) * WS + 32 * w + col];
    }

    const float b1r = b1[comp];
    const float w2r = W2[comp];

    float2 qp = ((const float2*)(x0 + (size_t)blk * 512))[comp];
    float q0 = qp.x, p0 = qp.y;
    if (iow) qsh[comp] = (_Float16)q0;
    __syncthreads();

    const float dt = 0.01f;
    float accq = 0.f, accp = 0.f, qs = q0, ps = p0;

    #pragma unroll 1
    for (int it = 0; it < NSTEPS * 4; ++it) {
        const int stg = it & 3;

        // ---- forward: z-tile-row w = (W^T q). B = q replicated over cols ----
        v16f Ca = {0}, Cb = {0};
        #pragma unroll
        for (int kk = 0; kk < 16; kk += 2) {
            v8h bq0 = *(const v8h*)(qsh + 16 * kk + 8 * half);        // bcast
            v8h bq1 = *(const v8h*)(qsh + 16 * (kk + 1) + 8 * half);  // bcast
            Ca = __builtin_amdgcn_mfma_f32_32x32x16_f16(wA[kk], bq0, Ca, 0, 0, 0);
            Cb = __builtin_amdgcn_mfma_f32_32x32x16_f16(wA[kk + 1], bq1, Cb, 0, 0, 0);
        }
        float z = pick16(Ca + Cb, r0, r2) + b1r;

        // ---- nonlinearity for owned comp ----
        float e = __expf(2.f * z);            // tanh via exp; saturates ok
        float hh = 1.f - 2.f / (e + 1.f);
        float u = (1.f - hh * hh) * w2r;
        if (iow) ush[comp] = (_Float16)u;
        __syncthreads();

        // ---- backward: g-tile-row w = (W u). B = u replicated over cols ----
        v16f Ga = {0}, Gb = {0};
        #pragma unroll
        for (int kk = 0; kk < 16; kk += 2) {
            v8h bu0 = *(const v8h*)(ush + 16 * kk + 8 * half);        // bcast
            v8h bu1 = *(const v8h*)(ush + 16 * (kk + 1) + 8 * half);  // bcast
            Ga = __builtin_amdgcn_mfma_f32_32x32x16_f16(wB[kk], bu0, Ga, 0, 0, 0);
            Gb = __builtin_amdgcn_mfma_f32_32x32x16_f16(wB[kk + 1], bu1, Gb, 0, 0, 0);
        }
        float g = pick16(Ga + Gb, r0, r2);

        // ---- RK4 bookkeeping for owned comp ----
        float kq = ps, kp = -g;
        float wgt = (stg == 0 || stg == 3) ? 1.f : 2.f;
        accq += wgt * kq;
        accp += wgt * kp;
        float qn;
        if (stg < 3) {
            float a = (stg == 2) ? dt : 0.5f * dt;
            qs = q0 + a * kq;
            ps = p0 + a * kp;
            qn = qs;
        } else {
            q0 += (dt / 6.f) * accq;
            p0 += (dt / 6.f) * accp;
            accq = 0.f; accp = 0.f;
            qs = q0; ps = p0;
            qn = q0;
        }
        if (iow) qsh[comp] = (_Float16)qn;
        __syncthreads();
    }

    if (iow)
        ((float2*)(out + (size_t)blk * 512))[comp] = make_float2(q0, p0);
}

extern "C" void kernel_launch(void* const* d_in, const int* in_sizes, int n_in,
                              void* d_out, int out_size, void* d_ws, size_t ws_size,
                              hipStream_t stream) {
    const float* x0 = (const float*)d_in[0];
    const float* W1 = (const float*)d_in[1];
    const float* b1 = (const float*)d_in[2];
    const float* W2 = (const float*)d_in[3];
    // d_in[4] = b2: constant offset, no effect on the gradient/dynamics.
    float* out = (float*)d_out;
    hipLaunchKernelGGL(ham_kernel, dim3(256), dim3(512), 0, stream,
                       x0, W1, b1, W2, out);
}

// Round 10
// 385.380 us; speedup vs baseline: 1.7684x; 1.7684x over previous
//
#include <hip/hip_runtime.h>
#include <stdint.h>

// HamiltonianFlow: x [256, 8, 32, 2] (q,p); H = 0.5*sum(p^2) + MLP(q).
// dq/dt = p, dp/dt = -W1 @ [(1-tanh(z)^2) * W2], z = q^T W1 + b1.
// 100 RK4 steps = 400 strictly sequential fwd+bwd 256x256 matvecs.
//
// R10. Cost model (recalibrated R9): MFMA pipe = 1015 FLOP/cyc/SIMD, so a
// 16x16x32 f16 MFMA = 16.1 cyc/SIMD and per-block-eval pipe floor is
// 2 dirs x 128 MFMA / 4 SIMD x 16.1 = 1033 cyc REGARDLESS of shape (total
// FLOP invariant; 32x32 shape was 2x FLOP/instr, same time -> R9 regressed
// only by idling). Levers left: overlap + serial-tail reduction.
//  - 16 waves (4/SIMD): late waves' MFMA issue covers early waves' tails.
//  - wave w owns tile w only: 8 MFMA per phase (short dep chain, 2 accums).
//  - BOTH dirs column-owned, zero extract/bounce:
//      fwd: A = q-replicated (uniform b128 reads), B = W^T frags
//           B[k=8q+j][n=s] = W[32kk+8q+j][16w+s]  -> D[.][s] = z[16w+s]
//      bwd: A = u-replicated, B = W-row frags
//           B[k=8q+j][n=s] = W[16w+s][32kk+8q+j] (contiguous b128 gather)
//           -> D[.][s] = g[16w+s]
//    lane's result = C[0]; comp = 16w+s (quads duplicate, no divergence).
// 2 barriers/eval. FULL unroll on all reg arrays (R4: dynamic idx => spill).
// Numerics: f16 storage, fp32 MFMA accumulate (R3/5/7/8 class, 1.95e-3).

typedef _Float16 v8h __attribute__((ext_vector_type(8)));
typedef _Float16 v4h __attribute__((ext_vector_type(4)));
typedef float v4f __attribute__((ext_vector_type(4)));

#define NSTEPS 100
#define WS 264   // padded f16 row stride (528 B: rows 16B-aligned, bank shift)

__global__ __launch_bounds__(1024, 4)
void ham_kernel(const float* __restrict__ x0, const float* __restrict__ W1,
                const float* __restrict__ b1, const float* __restrict__ W2,
                float* __restrict__ out)
{
    __shared__ __align__(16) _Float16 wlds[256 * WS];   // 135168 B staged W1
    __shared__ __align__(16) _Float16 qsh[256];
    __shared__ __align__(16) _Float16 ush[256];

    const int t = threadIdx.x;
    const int w = t >> 6;          // wave 0..15: owns tile w = comps [16w,16w+16)
    const int l = t & 63;
    const int quad = l >> 4;       // K-subgroup
    const int s = l & 15;          // owned column
    const int comp = 16 * w + s;   // owned component (dup across quads)
    const int blk = blockIdx.x;

    // ---- stage W1 -> LDS f16 (padded rows), coalesced ----
    #pragma unroll 1
    for (int k = t; k < 65536 / 4; k += 1024) {
        const int row = k >> 6, col4 = (k & 63) * 4;
        float4 v = ((const float4*)W1)[k];
        v4h h; h[0] = (_Float16)v.x; h[1] = (_Float16)v.y;
               h[2] = (_Float16)v.z; h[3] = (_Float16)v.w;
        *(v4h*)(wlds + row * WS + col4) = h;
    }
    __syncthreads();

    // ---- weight B-frags, both orientations, FULL unroll ----
    // wF[kk]  (fwd):  elem j = W[32kk+8quad+j][comp]   (column gather)
    // wBt[kk] (bwd):  elem j = W[comp][32kk+8quad+j]   (contiguous b128)
    v8h wF[8], wBt[8];
    #pragma unroll
    for (int kk = 0; kk < 8; ++kk) {
        wBt[kk] = *(const v8h*)(wlds + comp * WS + 32 * kk + 8 * quad);
        #pragma unroll
        for (int j = 0; j < 8; ++j)
            wF[kk][j] = wlds[(32 * kk + 8 * quad + j) * WS + comp];
    }

    const float b1r = b1[comp];
    const float w2r = W2[comp];

    float2 qp = ((const float2*)(x0 + (size_t)blk * 512))[comp];
    float q0 = qp.x, p0 = qp.y;
    if (quad == 0) qsh[comp] = (_Float16)q0;
    __syncthreads();

    const float dt = 0.01f;
    float accq = 0.f, accp = 0.f, qs = q0, ps = p0;

    #pragma unroll 1
    for (int it = 0; it < NSTEPS * 4; ++it) {
        const int stg = it & 3;

        // ---- forward: z[16w+s] via A=q-replicated, B=wF ----
        v4f Ca = {0, 0, 0, 0}, Cb = {0, 0, 0, 0};
        #pragma unroll
        for (int kk = 0; kk < 8; kk += 2) {
            v8h aq0 = *(const v8h*)(qsh + 32 * kk + 8 * quad);        // bcast
            v8h aq1 = *(const v8h*)(qsh + 32 * (kk + 1) + 8 * quad);  // bcast
            Ca = __builtin_amdgcn_mfma_f32_16x16x32_f16(aq0, wF[kk], Ca, 0, 0, 0);
            Cb = __builtin_amdgcn_mfma_f32_16x16x32_f16(aq1, wF[kk + 1], Cb, 0, 0, 0);
        }
        float z = Ca[0] + Cb[0] + b1r;   // D rows equal -> reg 0

        // ---- nonlinearity for owned comp (dup across quads) ----
        float e = __expf(2.f * z);            // tanh via exp; saturates ok
        float hh = 1.f - 2.f / (e + 1.f);
        float u = (1.f - hh * hh) * w2r;
        if (quad == 0) ush[comp] = (_Float16)u;
        __syncthreads();

        // ---- backward: g[16w+s] via A=u-replicated, B=wBt ----
        v4f Ga = {0, 0, 0, 0}, Gb = {0, 0, 0, 0};
        #pragma unroll
        for (int kk = 0; kk < 8; kk += 2) {
            v8h au0 = *(const v8h*)(ush + 32 * kk + 8 * quad);        // bcast
            v8h au1 = *(const v8h*)(ush + 32 * (kk + 1) + 8 * quad);  // bcast
            Ga = __builtin_amdgcn_mfma_f32_16x16x32_f16(au0, wBt[kk], Ga, 0, 0, 0);
            Gb = __builtin_amdgcn_mfma_f32_16x16x32_f16(au1, wBt[kk + 1], Gb, 0, 0, 0);
        }
        float g = Ga[0] + Gb[0];

        // ---- RK4 bookkeeping for owned comp ----
        float kq = ps, kp = -g;
        float wgt = (stg == 0 || stg == 3) ? 1.f : 2.f;
        accq += wgt * kq;
        accp += wgt * kp;
        float qn;
        if (stg < 3) {
            float a = (stg == 2) ? dt : 0.5f * dt;
            qs = q0 + a * kq;
            ps = p0 + a * kp;
            qn = qs;
        } else {
            q0 += (dt / 6.f) * accq;
            p0 += (dt / 6.f) * accp;
            accq = 0.f; accp = 0.f;
            qs = q0; ps = p0;
            qn = q0;
        }
        if (quad == 0) qsh[comp] = (_Float16)qn;
        __syncthreads();
    }

    if (quad == 0)
        ((float2*)(out + (size_t)blk * 512))[comp] = make_float2(q0, p0);
}

extern "C" void kernel_launch(void* const* d_in, const int* in_sizes, int n_in,
                              void* d_out, int out_size, void* d_ws, size_t ws_size,
                              hipStream_t stream) {
    const float* x0 = (const float*)d_in[0];
    const float* W1 = (const float*)d_in[1];
    const float* b1 = (const float*)d_in[2];
    const float* W2 = (const float*)d_in[3];
    // d_in[4] = b2: constant offset, no effect on the gradient/dynamics.
    float* out = (float*)d_out;
    hipLaunchKernelGGL(ham_kernel, dim3(256), dim3(1024), 0, stream,
                       x0, W1, b1, W2, out);
}